// Round 2
// baseline (232.691 us; speedup 1.0000x reference)
//
#include <hip/hip_runtime.h>

typedef __attribute__((ext_vector_type(8))) __bf16 bf16x8;
typedef __attribute__((ext_vector_type(4))) float f32x4;
typedef unsigned short u16;
typedef unsigned int u32;

#define NB 524288
#define PVS 116   // pv row stride (floats): 112 cols + 4 pad
#define HSS 72    // hs row stride (bf16): 64 cols + 8 pad
#define EPSI 1e-5f

__device__ __forceinline__ float fast_gelu(float v) {
    // tanh-form GELU; max |err| vs exact erf-GELU ~3e-4 in h-units, << 3e-2 threshold
    float t = 1.5957691216057308f * v * (1.0f + 0.044715f * v * v);
    float e = __expf(t);
    float th = 1.0f - 2.0f / (1.0f + e);
    return 0.5f * v * (1.0f + th);
}

template<typename T>
__device__ __forceinline__ void load8(const T* p, float* o);

template<>
__device__ __forceinline__ void load8<__bf16>(const __bf16* p, float* o) {
    bf16x8 r = *reinterpret_cast<const bf16x8*>(p);
#pragma unroll
    for (int i = 0; i < 8; ++i) o[i] = (float)r[i];
}
template<>
__device__ __forceinline__ void load8<float>(const float* p, float* o) {
    f32x4 a = *reinterpret_cast<const f32x4*>(p);
    f32x4 b = *reinterpret_cast<const f32x4*>(p + 4);
#pragma unroll
    for (int i = 0; i < 4; ++i) { o[i] = a[i]; o[4 + i] = b[i]; }
}

__device__ __forceinline__ bf16x8 to_bf(const float* o) {
    bf16x8 r;
#pragma unroll
    for (int i = 0; i < 8; ++i) r[i] = (__bf16)o[i];
    return r;
}

// ---- dtype probe: f32 tensors read as u16 have ~25% "bf16 exponent >= 0xC0" in even
// halves; genuine bf16 N(0,1) data has none. Flag=1 -> inputs are float32.
__global__ void detect_kernel(const u16* __restrict__ xr, int* __restrict__ flag) {
    int hits = 0;
    for (int i = threadIdx.x; i < 16384; i += 256) {
        u32 e = ((u32)xr[i] >> 7) & 0xFFu;
        hits += (e >= 0xC0u) ? 1 : 0;
    }
    __shared__ int red;
    if (threadIdx.x == 0) red = 0;
    __syncthreads();
    atomicAdd(&red, hits);
    __syncthreads();
    if (threadIdx.x == 0) *flag = (red >= 16) ? 1 : 0;
}

// ---- Pass 1: column sums / sum-of-squares of h_pre = x @ w_in^T (b_in cancels in BN)
template<typename T>
__device__ __forceinline__ void stats_body(const T* __restrict__ x,
                                           const T* __restrict__ w_in,
                                           float* __restrict__ ws,
                                           float* __restrict__ red) {
    const int lane = threadIdx.x & 63;
    const int wave = threadIdx.x >> 6;
    const int c = lane & 15;
    const int q = lane >> 4;
    float tmp[8];

    bf16x8 b1[4];
#pragma unroll
    for (int nt = 0; nt < 4; ++nt) {
        load8(w_in + (nt * 16 + c) * 32 + q * 8, tmp);
        b1[nt] = to_bf(tmp);
    }

    float accs[4][4], accq[4][4];
#pragma unroll
    for (int nt = 0; nt < 4; ++nt)
#pragma unroll
        for (int r = 0; r < 4; ++r) { accs[nt][r] = 0.f; accq[nt][r] = 0.f; }

    const int wid = blockIdx.x * 4 + wave;  // 0..4095
    for (int t = 0; t < 8; ++t) {
        const long row0 = ((long)wid * 8 + t) * 16;
        load8(x + (row0 + c) * 32 + q * 8, tmp);
        bf16x8 a1 = to_bf(tmp);
#pragma unroll
        for (int nt = 0; nt < 4; ++nt) {
            f32x4 z = {0.f, 0.f, 0.f, 0.f};
            f32x4 acc = __builtin_amdgcn_mfma_f32_16x16x32_bf16(a1, b1[nt], z, 0, 0, 0);
#pragma unroll
            for (int r = 0; r < 4; ++r) {
                float v = acc[r];
                accs[nt][r] += v;
                accq[nt][r] += v * v;
            }
        }
    }
    for (int i = threadIdx.x; i < 128; i += 256) red[i] = 0.f;
    __syncthreads();
#pragma unroll
    for (int nt = 0; nt < 4; ++nt) {
        float s  = accs[nt][0] + accs[nt][1] + accs[nt][2] + accs[nt][3];
        float sq = accq[nt][0] + accq[nt][1] + accq[nt][2] + accq[nt][3];
        s  += __shfl_xor(s, 16);  s  += __shfl_xor(s, 32);
        sq += __shfl_xor(sq, 16); sq += __shfl_xor(sq, 32);
        if (q == 0) {
            atomicAdd(&red[nt * 16 + c], s);
            atomicAdd(&red[64 + nt * 16 + c], sq);
        }
    }
    __syncthreads();
    for (int i = threadIdx.x; i < 128; i += 256) atomicAdd(&ws[i], red[i]);
}

__global__ __launch_bounds__(256) void stats_kernel(const void* x, const void* w_in,
                                                    float* ws, const int* flag) {
    __shared__ float red[128];
    if (*flag) stats_body<float>((const float*)x, (const float*)w_in, ws, red);
    else       stats_body<__bf16>((const __bf16*)x, (const __bf16*)w_in, ws, red);
}

// ---- Pass 1.5: fold BN into per-column scale/shift
__global__ void scale_kernel(const float* __restrict__ ws, const void* bn_g,
                             const void* bn_b, float* __restrict__ sc, const int* flag) {
    int j = threadIdx.x;  // 64 threads
    float mu  = ws[j] * (1.0f / NB);
    float var = ws[64 + j] * (1.0f / NB) - mu * mu;
    var = fmaxf(var, 0.0f);
    float g, b;
    if (*flag) { g = ((const float*)bn_g)[j]; b = ((const float*)bn_b)[j]; }
    else { g = (float)((const __bf16*)bn_g)[j]; b = (float)((const __bf16*)bn_b)[j]; }
    float s = g * rsqrtf(var + EPSI);
    sc[j]      = s;
    sc[64 + j] = b - mu * s;
}

// ---- Pass 2: GEMM1 -> BN+GELU -> GEMM2 (104 cols: fi0[32]|fs0[32]|lc[40]) -> epilogue
template<typename T>
__device__ __forceinline__ void main_body(
    const T* __restrict__ x, const T* __restrict__ w_in,
    const T* __restrict__ w_fi, const T* __restrict__ b_fi,
    const T* __restrict__ w_fs, const T* __restrict__ b_fs,
    const T* __restrict__ w_lc, const T* __restrict__ b_lc,
    const float* __restrict__ sc, void* __restrict__ outv,
    __bf16* __restrict__ hs, float* __restrict__ pv) {

    const int lane = threadIdx.x & 63;
    const int wave = threadIdx.x >> 6;
    const int c = lane & 15;
    const int q = lane >> 4;
    float tmp[8];

    bf16x8 b1[4];
#pragma unroll
    for (int nt = 0; nt < 4; ++nt) {
        load8(w_in + (nt * 16 + c) * 32 + q * 8, tmp);
        b1[nt] = to_bf(tmp);
    }

    // W2 rows = [w_fi[0:32] | w_fs[0:32] | w_lc[0:40] | zeros to 112]
    bf16x8 b2[7][2];
#pragma unroll
    for (int nt = 0; nt < 7; ++nt) {
        const int g = nt * 16 + c;
        const T* src = nullptr;
        if (g < 32)       src = w_fi + g * 64;
        else if (g < 64)  src = w_fs + (g - 32) * 64;
        else if (g < 104) src = w_lc + (g - 64) * 64;
#pragma unroll
        for (int kt = 0; kt < 2; ++kt) {
            if (src) {
                load8(src + kt * 32 + q * 8, tmp);
                b2[nt][kt] = to_bf(tmp);
            } else {
                bf16x8 z;
#pragma unroll
                for (int i = 0; i < 8; ++i) z[i] = (__bf16)0.0f;
                b2[nt][kt] = z;
            }
        }
    }

    float scale_r[4], shift_r[4];
#pragma unroll
    for (int nt = 0; nt < 4; ++nt) {
        scale_r[nt] = sc[nt * 16 + c];
        shift_r[nt] = sc[64 + nt * 16 + c];
    }

    float bfi_r[8], bfs_r[8], blc_r[10];
#pragma unroll
    for (int i = 0; i < 8; ++i) {
        bfi_r[i] = (float)b_fi[q * 8 + i];
        bfs_r[i] = (float)b_fs[q * 8 + i];
    }
#pragma unroll
    for (int i = 0; i < 10; ++i) blc_r[i] = (float)b_lc[q * 10 + i];

    const int wid = blockIdx.x * 4 + wave;  // 0..8191
    for (int t = 0; t < 4; ++t) {
        const long row0 = ((long)wid * 4 + t) * 16;
        float a1f[8];
        load8(x + (row0 + c) * 32 + q * 8, a1f);
        bf16x8 a1 = to_bf(a1f);

        f32x4 h4[4];
#pragma unroll
        for (int nt = 0; nt < 4; ++nt) {
            f32x4 z = {0.f, 0.f, 0.f, 0.f};
            h4[nt] = __builtin_amdgcn_mfma_f32_16x16x32_bf16(a1, b1[nt], z, 0, 0, 0);
        }
        // C-layout: row=4q+r, col=16nt+c -> hs[batch_row][feat]
#pragma unroll
        for (int nt = 0; nt < 4; ++nt) {
#pragma unroll
            for (int r = 0; r < 4; ++r) {
                float v = h4[nt][r] * scale_r[nt] + shift_r[nt];
                hs[(q * 4 + r) * HSS + nt * 16 + c] = (__bf16)fast_gelu(v);
            }
        }
        __syncthreads();

        bf16x8 a2[2];
#pragma unroll
        for (int kt = 0; kt < 2; ++kt)
            a2[kt] = *reinterpret_cast<const bf16x8*>(hs + c * HSS + kt * 32 + q * 8);

#pragma unroll
        for (int nt = 0; nt < 7; ++nt) {
            f32x4 acc = {0.f, 0.f, 0.f, 0.f};
            acc = __builtin_amdgcn_mfma_f32_16x16x32_bf16(a2[0], b2[nt][0], acc, 0, 0, 0);
            acc = __builtin_amdgcn_mfma_f32_16x16x32_bf16(a2[1], b2[nt][1], acc, 0, 0, 0);
#pragma unroll
            for (int r = 0; r < 4; ++r)
                pv[(q * 4 + r) * PVS + nt * 16 + c] = acc[r];
        }
        __syncthreads();

        // Epilogue: lane (c,q) handles batch row c, strip q
        const float* prow = pv + c * PVS;
        float fi[8];
        {
            f32x4 t0 = *reinterpret_cast<const f32x4*>(prow + q * 8);
            f32x4 t1 = *reinterpret_cast<const f32x4*>(prow + q * 8 + 4);
#pragma unroll
            for (int i = 0; i < 4; ++i) { fi[i] = t0[i] + bfi_r[i]; fi[4 + i] = t1[i] + bfi_r[4 + i]; }
        }
        float m = fi[0];
#pragma unroll
        for (int i = 1; i < 8; ++i) m = fmaxf(m, fi[i]);
        m = fmaxf(m, __shfl_xor(m, 16));
        m = fmaxf(m, __shfl_xor(m, 32));

        float fs[8];
        {
            f32x4 t0 = *reinterpret_cast<const f32x4*>(prow + 32 + q * 8);
            f32x4 t1 = *reinterpret_cast<const f32x4*>(prow + 32 + q * 8 + 4);
#pragma unroll
            for (int i = 0; i < 4; ++i) { fs[i] = t0[i] + bfs_r[i]; fs[4 + i] = t1[i] + bfs_r[4 + i]; }
        }
        float es = 0.f, dp = 0.f;
#pragma unroll
        for (int i = 0; i < 8; ++i) {
            float e = __expf(fi[i] - m);
            es += e;
            dp += e * (a1f[i] - fs[i]);  // a1f = x[row0+c][8q..8q+7], this lane's strip
        }
        es += __shfl_xor(es, 16); es += __shfl_xor(es, 32);
        dp += __shfl_xor(dp, 16); dp += __shfl_xor(dp, 32);
        float d  = dp / es;
        float sd = 1.0f / (1.0f + __expf(-d));
        // NODE_IDX==0 everywhere; leaves {0,1}: sd^2, {2,3}: sd(1-sd). Lane q owns leaf q.
        float coeff = (q < 2) ? sd * sd : sd * (1.0f - sd);

        float o[10];
#pragma unroll
        for (int i = 0; i < 10; ++i)
            o[i] = coeff * (prow[64 + q * 10 + i] + blc_r[i]);
#pragma unroll
        for (int i = 0; i < 10; ++i) {
            o[i] += __shfl_xor(o[i], 16);
            o[i] += __shfl_xor(o[i], 32);
        }
        if (q == 0) {
            if constexpr (sizeof(T) == 4) {
                float* op = (float*)outv + (row0 + c) * 10;
#pragma unroll
                for (int i = 0; i < 10; ++i) op[i] = o[i];
            } else {
                u32* op = reinterpret_cast<u32*>((u16*)outv + (row0 + c) * 10);
#pragma unroll
                for (int i = 0; i < 5; ++i) {
                    u32 lo = (u32)__builtin_bit_cast(u16, (__bf16)o[2 * i]);
                    u32 hi = (u32)__builtin_bit_cast(u16, (__bf16)o[2 * i + 1]);
                    op[i] = lo | (hi << 16);
                }
            }
        }
        __syncthreads();
    }
}

__global__ __launch_bounds__(256) void main_kernel(
    const void* x, const void* w_in, const void* w_fi, const void* b_fi,
    const void* w_fs, const void* b_fs, const void* w_lc, const void* b_lc,
    const float* sc, void* outv, const int* flag) {
    __shared__ __bf16 hs_all[4][16 * HSS];
    __shared__ float  pv_all[4][16 * PVS];
    const int wave = threadIdx.x >> 6;
    if (*flag)
        main_body<float>((const float*)x, (const float*)w_in, (const float*)w_fi,
                         (const float*)b_fi, (const float*)w_fs, (const float*)b_fs,
                         (const float*)w_lc, (const float*)b_lc, sc, outv,
                         hs_all[wave], pv_all[wave]);
    else
        main_body<__bf16>((const __bf16*)x, (const __bf16*)w_in, (const __bf16*)w_fi,
                          (const __bf16*)b_fi, (const __bf16*)w_fs, (const __bf16*)b_fs,
                          (const __bf16*)w_lc, (const __bf16*)b_lc, sc, outv,
                          hs_all[wave], pv_all[wave]);
}

extern "C" void kernel_launch(void* const* d_in, const int* in_sizes, int n_in,
                              void* d_out, int out_size, void* d_ws, size_t ws_size,
                              hipStream_t stream) {
    float* ws = (float*)d_ws;
    int* flag = (int*)(ws + 256);

    hipMemsetAsync(d_ws, 0, 128 * sizeof(float), stream);
    detect_kernel<<<1, 256, 0, stream>>>((const u16*)d_in[0], flag);
    stats_kernel<<<1024, 256, 0, stream>>>(d_in[0], d_in[1], ws, flag);
    scale_kernel<<<1, 64, 0, stream>>>(ws, d_in[3], d_in[4], ws + 128, flag);
    main_kernel<<<2048, 256, 0, stream>>>(d_in[0], d_in[1], d_in[5], d_in[6],
                                          d_in[7], d_in[8], d_in[9], d_in[10],
                                          ws + 128, d_out, flag);
}

// Round 3
// 206.460 us; speedup vs baseline: 1.1271x; 1.1271x over previous
//
#include <hip/hip_runtime.h>

typedef __attribute__((ext_vector_type(8))) __bf16 bf16x8;
typedef __attribute__((ext_vector_type(4))) float f32x4;
typedef unsigned short u16;
typedef unsigned int u32;

#define NB 524288
#define HSS 72    // hs row stride (bf16): 64 cols + 8 pad
#define EPSI 1e-5f

__device__ __forceinline__ float bf2f(u16 h) {
    union { u32 u; float f; } cv; cv.u = ((u32)h) << 16; return cv.f;
}
__device__ __forceinline__ u16 f2bf(float f) {
    __bf16 b = (__bf16)f; return __builtin_bit_cast(u16, b);
}
__device__ __forceinline__ float ldany(const void* p, long i, int isf) {
    return isf ? ((const float*)p)[i] : bf2f(((const u16*)p)[i]);
}

// gelu_tanh = v * sigmoid(1.5957691*v*(1+0.044715 v^2)); |err| vs erf-gelu ~3e-4
__device__ __forceinline__ float fast_gelu(float v) {
    float t = 1.5957691216057308f * v * (1.0f + 0.044715f * v * v);
    float en = __expf(-t);
    return v * __builtin_amdgcn_rcpf(1.0f + en);
}

__device__ __forceinline__ bf16x8 loadfrag(const __bf16* p) {
    return *reinterpret_cast<const bf16x8*>(p);
}
__device__ __forceinline__ bf16x8 loadfrag(const float* p) {
    f32x4 a = *reinterpret_cast<const f32x4*>(p);
    f32x4 b = *reinterpret_cast<const f32x4*>(p + 4);
    bf16x8 r;
#pragma unroll
    for (int i = 0; i < 4; ++i) { r[i] = (__bf16)a[i]; r[4 + i] = (__bf16)b[i]; }
    return r;
}

// ---- pack: dtype-detect + zero stat sums + pack W1/W2(bf16, u/v leaf-pairs folded) + biases
__global__ __launch_bounds__(256) void pack_kernel(
    const void* x, const void* w_in, const void* w_fi, const void* b_fi,
    const void* w_fs, const void* b_fs, const void* w_lc, const void* b_lc,
    float* __restrict__ ws)
{
    const int tid = threadIdx.x;
    __shared__ int redf;
    if (tid == 0) redf = 0;
    __syncthreads();
    int hits = 0;
    const u16* xr = (const u16*)x;
    for (int i = tid; i < 16384; i += 256) {
        u32 e = ((u32)xr[i] >> 7) & 0xFFu;
        hits += (e >= 0xC0u) ? 1 : 0;   // f32-as-u16 low halves: ~25% hit; true bf16: 0
    }
    atomicAdd(&redf, hits);
    __syncthreads();
    const int isf = (redf >= 16) ? 1 : 0;
    if (tid == 0) ((int*)ws)[256] = isf;

    for (int i = tid; i < 128; i += 256) ws[i] = 0.f;  // stat sums

    float* biasP = ws + 288;   // [96] aligned with g layout: fi0|fi1|fs0|fs1|u|v
    for (int g = tid; g < 96; g += 256) {
        float v = 0.f;
        if (g < 32)                 v = ldany(b_fi, g, isf);
        else if (g < 64)            v = ldany(b_fs, g - 32, isf);
        else if (g < 74)            v = ldany(b_lc, g - 64, isf) + ldany(b_lc, g - 54, isf);
        else if (g >= 80 && g < 90) v = ldany(b_lc, g - 60, isf) + ldany(b_lc, g - 50, isf);
        biasP[g] = v;
    }

    u16* W2p = (u16*)(ws + 384);   // 96 rows x 64 cols bf16
    u16* W1p = W2p + 6144;         // 64 rows x 32 cols bf16
    for (int idx = tid; idx < 6144; idx += 256) {
        int g = idx >> 6, f = idx & 63;
        float v = 0.f;
        if (g < 32)                 v = ldany(w_fi, (long)g * 64 + f, isf);
        else if (g < 64)            v = ldany(w_fs, (long)(g - 32) * 64 + f, isf);
        else if (g < 74)            v = ldany(w_lc, (long)(g - 64) * 64 + f, isf)
                                      + ldany(w_lc, (long)(g - 54) * 64 + f, isf);
        else if (g >= 80 && g < 90) v = ldany(w_lc, (long)(g - 60) * 64 + f, isf)
                                      + ldany(w_lc, (long)(g - 50) * 64 + f, isf);
        W2p[idx] = f2bf(v);
    }
    for (int idx = tid; idx < 2048; idx += 256)
        W1p[idx] = f2bf(ldany(w_in, idx, isf));
}

// ---- stats: column sums / sumsq of h_pre = x @ w_in^T (b_in cancels in BN)
template<typename T>
__device__ __forceinline__ void stats_body(const T* __restrict__ x,
                                           const u16* __restrict__ W1p,
                                           float* __restrict__ ws,
                                           float* __restrict__ red) {
    const int lane = threadIdx.x & 63;
    const int wave = threadIdx.x >> 6;
    const int c = lane & 15;
    const int q = lane >> 4;

    bf16x8 b1[4];
#pragma unroll
    for (int nt = 0; nt < 4; ++nt)
        b1[nt] = *reinterpret_cast<const bf16x8*>(W1p + (nt * 16 + c) * 32 + q * 8);

    float accs[4][4], accq[4][4];
#pragma unroll
    for (int nt = 0; nt < 4; ++nt)
#pragma unroll
        for (int r = 0; r < 4; ++r) { accs[nt][r] = 0.f; accq[nt][r] = 0.f; }

    const int wid = blockIdx.x * 4 + wave;  // 0..4095 (1024 blocks)
    for (int t = 0; t < 8; ++t) {
        const long row0 = ((long)wid * 8 + t) * 16;
        bf16x8 a1 = loadfrag(x + (row0 + c) * 32 + q * 8);
#pragma unroll
        for (int nt = 0; nt < 4; ++nt) {
            f32x4 z = {0.f, 0.f, 0.f, 0.f};
            f32x4 acc = __builtin_amdgcn_mfma_f32_16x16x32_bf16(a1, b1[nt], z, 0, 0, 0);
#pragma unroll
            for (int r = 0; r < 4; ++r) {
                float v = acc[r];
                accs[nt][r] += v;
                accq[nt][r] += v * v;
            }
        }
    }
    for (int i = threadIdx.x; i < 128; i += 256) red[i] = 0.f;
    __syncthreads();
#pragma unroll
    for (int nt = 0; nt < 4; ++nt) {
        float s  = accs[nt][0] + accs[nt][1] + accs[nt][2] + accs[nt][3];
        float sq = accq[nt][0] + accq[nt][1] + accq[nt][2] + accq[nt][3];
        s  += __shfl_xor(s, 16);  s  += __shfl_xor(s, 32);
        sq += __shfl_xor(sq, 16); sq += __shfl_xor(sq, 32);
        if (q == 0) {
            atomicAdd(&red[nt * 16 + c], s);
            atomicAdd(&red[64 + nt * 16 + c], sq);
        }
    }
    __syncthreads();
    for (int i = threadIdx.x; i < 128; i += 256) atomicAdd(&ws[i], red[i]);
}

__global__ __launch_bounds__(256) void stats_kernel(const void* x, float* ws) {
    __shared__ float red[128];
    const u16* W1p = (const u16*)(ws + 384) + 6144;
    if (((const int*)ws)[256]) stats_body<float>((const float*)x, W1p, ws, red);
    else                       stats_body<__bf16>((const __bf16*)x, W1p, ws, red);
}

// ---- main: 1 wave/block. GEMM1 -> BN+GELU -> hs LDS -> GEMM2(6 tiles) -> C-layout epilogue
template<typename T>
__device__ __forceinline__ void main_body(
    const T* __restrict__ x, const T* __restrict__ bn_g, const T* __restrict__ bn_b,
    const float* __restrict__ sums, const float* __restrict__ biasP,
    const u16* __restrict__ W1p, const u16* __restrict__ W2p,
    T* __restrict__ out, __bf16* __restrict__ hs)
{
    const int lane = threadIdx.x & 63;
    const int c = lane & 15;
    const int q = lane >> 4;

    bf16x8 b1[4];
#pragma unroll
    for (int nt = 0; nt < 4; ++nt)
        b1[nt] = *reinterpret_cast<const bf16x8*>(W1p + (nt * 16 + c) * 32 + q * 8);

    bf16x8 b2[6][2];
#pragma unroll
    for (int nt = 0; nt < 6; ++nt)
#pragma unroll
        for (int kt = 0; kt < 2; ++kt)
            b2[nt][kt] = *reinterpret_cast<const bf16x8*>(W2p + (nt * 16 + c) * 64 + kt * 32 + q * 8);

    // BN scale/shift recomputed per wave from sums (cheap: 4 cols/lane)
    float scale_r[4], shift_r[4];
#pragma unroll
    for (int nt = 0; nt < 4; ++nt) {
        int j = nt * 16 + c;
        float mu  = sums[j] * (1.0f / NB);
        float var = fmaxf(sums[64 + j] * (1.0f / NB) - mu * mu, 0.0f);
        float s = (float)bn_g[j] * rsqrtf(var + EPSI);
        scale_r[nt] = s;
        shift_r[nt] = (float)bn_b[j] - mu * s;
    }

    const float bfi0 = biasP[c],      bfi1 = biasP[16 + c];
    const float bfs0 = biasP[32 + c], bfs1 = biasP[48 + c];
    const float bu   = biasP[64 + c], bv   = biasP[80 + c];

    const long wid = blockIdx.x;
    for (int t = 0; t < 4; ++t) {
        const long row0 = (wid * 4 + t) * 16;
        bf16x8 a1 = loadfrag(x + (row0 + c) * 32 + q * 8);

        f32x4 h4[4];
#pragma unroll
        for (int nt = 0; nt < 4; ++nt) {
            f32x4 z = {0.f, 0.f, 0.f, 0.f};
            h4[nt] = __builtin_amdgcn_mfma_f32_16x16x32_bf16(a1, b1[nt], z, 0, 0, 0);
        }
        // C-layout: row=4q+r, col=16nt+c
#pragma unroll
        for (int nt = 0; nt < 4; ++nt)
#pragma unroll
            for (int r = 0; r < 4; ++r) {
                float v = h4[nt][r] * scale_r[nt] + shift_r[nt];
                hs[(q * 4 + r) * HSS + nt * 16 + c] = (__bf16)fast_gelu(v);
            }
        __syncthreads();  // 1-wave block: lgkmcnt drain + free s_barrier

        bf16x8 a2_0 = *reinterpret_cast<const bf16x8*>(hs + c * HSS + q * 8);
        bf16x8 a2_1 = *reinterpret_cast<const bf16x8*>(hs + c * HSS + 32 + q * 8);

        f32x4 acc[6];
#pragma unroll
        for (int nt = 0; nt < 6; ++nt) {
            f32x4 z = {0.f, 0.f, 0.f, 0.f};
            acc[nt] = __builtin_amdgcn_mfma_f32_16x16x32_bf16(a2_0, b2[nt][0], z, 0, 0, 0);
            acc[nt] = __builtin_amdgcn_mfma_f32_16x16x32_bf16(a2_1, b2[nt][1], acc[nt], 0, 0, 0);
        }

        // x reload in C-layout (L1-hot): xv[nt][r] = x[row0+4q+r][16nt+c]
        float xv0[4], xv1[4];
#pragma unroll
        for (int r = 0; r < 4; ++r) {
            xv0[r] = (float)x[(row0 + q * 4 + r) * 32 + c];
            xv1[r] = (float)x[(row0 + q * 4 + r) * 32 + 16 + c];
        }

#pragma unroll
        for (int r = 0; r < 4; ++r) {
            // no max-subtraction: |fi| bounded << 87, exp safe in f32
            float e0  = __expf(acc[0][r] + bfi0);
            float e1  = __expf(acc[1][r] + bfi1);
            float fs0 = acc[2][r] + bfs0;
            float fs1 = acc[3][r] + bfs1;
            float es = e0 + e1;
            float dp = e0 * (xv0[r] - fs0) + e1 * (xv1[r] - fs1);
#pragma unroll
            for (int m = 1; m < 16; m <<= 1) {
                es += __shfl_xor(es, m);
                dp += __shfl_xor(dp, m);
            }
            float d  = dp * __builtin_amdgcn_rcpf(es);
            float sd = __builtin_amdgcn_rcpf(1.0f + __expf(-d));
            float uu = acc[4][r] + bu, vv = acc[5][r] + bv;
            float o = sd * (vv + sd * (uu - vv));  // sd^2*u + sd(1-sd)*v
            if (c < 10) out[(row0 + q * 4 + r) * 10 + c] = (T)o;
        }
        __syncthreads();  // WAR guard before next tile's hs overwrite (free, 1 wave)
    }
}

__global__ __launch_bounds__(64) void main_kernel(
    const void* x, const void* bn_g, const void* bn_b, float* ws, void* outv)
{
    __shared__ __attribute__((aligned(16))) __bf16 hs[16 * HSS];
    const float* biasP = ws + 288;
    const u16* W2p = (const u16*)(ws + 384);
    const u16* W1p = W2p + 6144;
    if (((const int*)ws)[256])
        main_body<float>((const float*)x, (const float*)bn_g, (const float*)bn_b,
                         ws, biasP, W1p, W2p, (float*)outv, hs);
    else
        main_body<__bf16>((const __bf16*)x, (const __bf16*)bn_g, (const __bf16*)bn_b,
                          ws, biasP, W1p, W2p, (__bf16*)outv, hs);
}

extern "C" void kernel_launch(void* const* d_in, const int* in_sizes, int n_in,
                              void* d_out, int out_size, void* d_ws, size_t ws_size,
                              hipStream_t stream) {
    float* ws = (float*)d_ws;
    pack_kernel<<<1, 256, 0, stream>>>(d_in[0], d_in[1], d_in[5], d_in[6],
                                       d_in[7], d_in[8], d_in[9], d_in[10], ws);
    stats_kernel<<<1024, 256, 0, stream>>>(d_in[0], ws);
    main_kernel<<<8192, 64, 0, stream>>>(d_in[0], d_in[3], d_in[4], ws, d_out);
}

// Round 4
// 180.800 us; speedup vs baseline: 1.2870x; 1.1419x over previous
//
#include <hip/hip_runtime.h>

typedef __attribute__((ext_vector_type(8))) __bf16 bf16x8;
typedef __attribute__((ext_vector_type(4))) float f32x4;
typedef unsigned short u16;
typedef unsigned int u32;

#define NB 524288
#define HSS 72    // hs row stride (bf16): 64 cols + 8 pad
#define EPSI 1e-5f

__device__ __forceinline__ float bf2f(u16 h) {
    union { u32 u; float f; } cv; cv.u = ((u32)h) << 16; return cv.f;
}
__device__ __forceinline__ u16 f2bf(float f) {
    __bf16 b = (__bf16)f; return __builtin_bit_cast(u16, b);
}
__device__ __forceinline__ float ldany(const void* p, long i, int isf) {
    return isf ? ((const float*)p)[i] : bf2f(((const u16*)p)[i]);
}

// gelu_tanh = v * sigmoid(1.5957691*v*(1+0.044715 v^2)); |err| vs erf-gelu ~3e-4
__device__ __forceinline__ float fast_gelu(float v) {
    float t = 1.5957691216057308f * v * (1.0f + 0.044715f * v * v);
    float en = __expf(-t);
    return v * __builtin_amdgcn_rcpf(1.0f + en);
}

__device__ __forceinline__ bf16x8 loadfrag(const __bf16* p) {
    return *reinterpret_cast<const bf16x8*>(p);
}
__device__ __forceinline__ bf16x8 loadfrag(const float* p) {
    f32x4 a = *reinterpret_cast<const f32x4*>(p);
    f32x4 b = *reinterpret_cast<const f32x4*>(p + 4);
    bf16x8 r;
#pragma unroll
    for (int i = 0; i < 4; ++i) { r[i] = (__bf16)a[i]; r[4 + i] = (__bf16)b[i]; }
    return r;
}

// Per-wave dtype self-detect from x[0:128] dwords: low u16 of each dword is a
// random f32 mantissa slice (P(exp>=0xC0)~0.25/sample, 128 samples) vs bf16 N(0,1)
// pairs (exp>=0xC0 means |v|>=2^65: never). P(miss) < 1e-14.
__device__ __forceinline__ int detect_isf(const void* x) {
    const int lane = threadIdx.x & 63;
    u32 w0 = ((const u32*)x)[lane];
    u32 w1 = ((const u32*)x)[64 + lane];
    int hit = ((((w0 >> 7) & 0xFFu) >= 0xC0u) || (((w1 >> 7) & 0xFFu) >= 0xC0u)) ? 1 : 0;
    return __ballot(hit) != 0ull;
}

// ---- stats (+pack): column sums/sumsq of h_pre = x @ w_in^T; blocks 0..24 also pack
template<typename T>
__device__ __forceinline__ void stats_body(const T* __restrict__ x,
                                           const T* __restrict__ w_in,
                                           float* __restrict__ ws,
                                           float* __restrict__ red) {
    const int lane = threadIdx.x & 63;
    const int wave = threadIdx.x >> 6;
    const int c = lane & 15;
    const int q = lane >> 4;

    bf16x8 b1[4];
#pragma unroll
    for (int nt = 0; nt < 4; ++nt)
        b1[nt] = loadfrag(w_in + (nt * 16 + c) * 32 + q * 8);

    float accs[4][4], accq[4][4];
#pragma unroll
    for (int nt = 0; nt < 4; ++nt)
#pragma unroll
        for (int r = 0; r < 4; ++r) { accs[nt][r] = 0.f; accq[nt][r] = 0.f; }

    const int wid = blockIdx.x * 4 + wave;  // 0..4095
    for (int t = 0; t < 8; ++t) {
        const long row0 = ((long)wid * 8 + t) * 16;
        bf16x8 a1 = loadfrag(x + (row0 + c) * 32 + q * 8);
#pragma unroll
        for (int nt = 0; nt < 4; ++nt) {
            f32x4 z = {0.f, 0.f, 0.f, 0.f};
            f32x4 acc = __builtin_amdgcn_mfma_f32_16x16x32_bf16(a1, b1[nt], z, 0, 0, 0);
#pragma unroll
            for (int r = 0; r < 4; ++r) {
                float v = acc[r];
                accs[nt][r] += v;
                accq[nt][r] += v * v;
            }
        }
    }
    for (int i = threadIdx.x; i < 128; i += 256) red[i] = 0.f;
    __syncthreads();
#pragma unroll
    for (int nt = 0; nt < 4; ++nt) {
        float s  = accs[nt][0] + accs[nt][1] + accs[nt][2] + accs[nt][3];
        float sq = accq[nt][0] + accq[nt][1] + accq[nt][2] + accq[nt][3];
        s  += __shfl_xor(s, 16);  s  += __shfl_xor(s, 32);
        sq += __shfl_xor(sq, 16); sq += __shfl_xor(sq, 32);
        if (q == 0) {
            atomicAdd(&red[nt * 16 + c], s);
            atomicAdd(&red[64 + nt * 16 + c], sq);
        }
    }
    __syncthreads();
    for (int i = threadIdx.x; i < 128; i += 256) atomicAdd(&ws[i], red[i]);
}

__global__ __launch_bounds__(256) void stats_kernel(
    const void* x, const void* w_in, const void* w_fi, const void* b_fi,
    const void* w_fs, const void* b_fs, const void* w_lc, const void* b_lc,
    float* __restrict__ ws)
{
    const int isf = detect_isf(x);

    // pack W2 (96x64 bf16, u/v leaf-pairs folded) across blocks 0..23; biases block 24
    if (blockIdx.x < 24) {
        u16* W2p = (u16*)(ws + 384);
        const int idx = blockIdx.x * 256 + threadIdx.x;   // 0..6143
        const int g = idx >> 6, f = idx & 63;
        float v = 0.f;
        if (g < 32)                 v = ldany(w_fi, (long)g * 64 + f, isf);
        else if (g < 64)            v = ldany(w_fs, (long)(g - 32) * 64 + f, isf);
        else if (g < 74)            v = ldany(w_lc, (long)(g - 64) * 64 + f, isf)
                                      + ldany(w_lc, (long)(g - 54) * 64 + f, isf);
        else if (g >= 80 && g < 90) v = ldany(w_lc, (long)(g - 60) * 64 + f, isf)
                                      + ldany(w_lc, (long)(g - 50) * 64 + f, isf);
        W2p[idx] = f2bf(v);
    } else if (blockIdx.x == 24 && threadIdx.x < 96) {
        float* biasP = ws + 288;
        const int g = threadIdx.x;
        float v = 0.f;
        if (g < 32)                 v = ldany(b_fi, g, isf);
        else if (g < 64)            v = ldany(b_fs, g - 32, isf);
        else if (g < 74)            v = ldany(b_lc, g - 64, isf) + ldany(b_lc, g - 54, isf);
        else if (g >= 80 && g < 90) v = ldany(b_lc, g - 60, isf) + ldany(b_lc, g - 50, isf);
        biasP[g] = v;
    }

    __shared__ float red[128];
    if (isf) stats_body<float>((const float*)x, (const float*)w_in, ws, red);
    else     stats_body<__bf16>((const __bf16*)x, (const __bf16*)w_in, ws, red);
}

// ---- main: 1 wave/block, 8 tiles, no barriers (in-order per-wave DS pipe), dbuf hs
template<typename T>
__device__ __forceinline__ void main_body(
    const T* __restrict__ x, const T* __restrict__ bn_g, const T* __restrict__ bn_b,
    const T* __restrict__ w_in, const float* __restrict__ ws,
    T* __restrict__ out, __bf16* __restrict__ hs0, __bf16* __restrict__ hs1)
{
    const int lane = threadIdx.x & 63;
    const int c = lane & 15;
    const int q = lane >> 4;
    const float* biasP = ws + 288;
    const u16* W2p = (const u16*)(ws + 384);

    bf16x8 b1[4];
#pragma unroll
    for (int nt = 0; nt < 4; ++nt)
        b1[nt] = loadfrag(w_in + (nt * 16 + c) * 32 + q * 8);

    bf16x8 b2[6][2];
#pragma unroll
    for (int nt = 0; nt < 6; ++nt)
#pragma unroll
        for (int kt = 0; kt < 2; ++kt)
            b2[nt][kt] = *reinterpret_cast<const bf16x8*>(W2p + (nt * 16 + c) * 64 + kt * 32 + q * 8);

    float scale_r[4], shift_r[4];
#pragma unroll
    for (int nt = 0; nt < 4; ++nt) {
        int j = nt * 16 + c;
        float mu  = ws[j] * (1.0f / NB);
        float var = fmaxf(ws[64 + j] * (1.0f / NB) - mu * mu, 0.0f);
        float s = (float)bn_g[j] * rsqrtf(var + EPSI);
        scale_r[nt] = s;
        shift_r[nt] = (float)bn_b[j] - mu * s;
    }

    const float bfi0 = biasP[c],      bfi1 = biasP[16 + c];
    const float bfs0 = biasP[32 + c], bfs1 = biasP[48 + c];
    const float bu   = biasP[64 + c], bv   = biasP[80 + c];

    const long wid = blockIdx.x;
#pragma unroll 2
    for (int t = 0; t < 8; ++t) {
        __bf16* hs = (t & 1) ? hs1 : hs0;
        const long row0 = wid * 128 + (long)t * 16;
        bf16x8 a1 = loadfrag(x + (row0 + c) * 32 + q * 8);

        // x in C-layout for epilogue (L1-hot: same lines as a1 across the wave)
        float xv0[4], xv1[4];
#pragma unroll
        for (int r = 0; r < 4; ++r) {
            xv0[r] = (float)x[(row0 + q * 4 + r) * 32 + c];
            xv1[r] = (float)x[(row0 + q * 4 + r) * 32 + 16 + c];
        }

        f32x4 h4[4];
#pragma unroll
        for (int nt = 0; nt < 4; ++nt) {
            f32x4 z = {0.f, 0.f, 0.f, 0.f};
            h4[nt] = __builtin_amdgcn_mfma_f32_16x16x32_bf16(a1, b1[nt], z, 0, 0, 0);
        }
        // C-layout: row=4q+r, col=16nt+c
#pragma unroll
        for (int nt = 0; nt < 4; ++nt)
#pragma unroll
            for (int r = 0; r < 4; ++r) {
                float v = h4[nt][r] * scale_r[nt] + shift_r[nt];
                hs[(q * 4 + r) * HSS + nt * 16 + c] = (__bf16)fast_gelu(v);
            }
        __asm__ volatile("" ::: "memory");  // keep hs writes before reads; HW DS pipe is in-order per wave

        bf16x8 a2_0 = *reinterpret_cast<const bf16x8*>(hs + c * HSS + q * 8);
        bf16x8 a2_1 = *reinterpret_cast<const bf16x8*>(hs + c * HSS + 32 + q * 8);

        f32x4 acc[6];
#pragma unroll
        for (int nt = 0; nt < 6; ++nt) {
            f32x4 z = {0.f, 0.f, 0.f, 0.f};
            acc[nt] = __builtin_amdgcn_mfma_f32_16x16x32_bf16(a2_0, b2[nt][0], z, 0, 0, 0);
            acc[nt] = __builtin_amdgcn_mfma_f32_16x16x32_bf16(a2_1, b2[nt][1], acc[nt], 0, 0, 0);
        }

#pragma unroll
        for (int r = 0; r < 4; ++r) {
            // no max-subtraction: |fi| bounded << 87, f32 exp safe
            float e0  = __expf(acc[0][r] + bfi0);
            float e1  = __expf(acc[1][r] + bfi1);
            float fs0 = acc[2][r] + bfs0;
            float fs1 = acc[3][r] + bfs1;
            float es = e0 + e1;
            float dp = e0 * (xv0[r] - fs0) + e1 * (xv1[r] - fs1);
#pragma unroll
            for (int m = 1; m < 16; m <<= 1) {
                es += __shfl_xor(es, m);
                dp += __shfl_xor(dp, m);
            }
            float d  = dp * __builtin_amdgcn_rcpf(es);
            float sd = __builtin_amdgcn_rcpf(1.0f + __expf(-d));
            float uu = acc[4][r] + bu, vv = acc[5][r] + bv;
            float o = sd * (vv + sd * (uu - vv));  // sd^2*u + sd(1-sd)*v
            if (c < 10) out[(row0 + q * 4 + r) * 10 + c] = (T)o;
        }
        __asm__ volatile("" ::: "memory");  // WAR: next write to this buffer is 2 tiles away
    }
}

__global__ __launch_bounds__(64, 4) void main_kernel(
    const void* x, const void* bn_g, const void* bn_b, const void* w_in,
    float* ws, void* outv)
{
    __shared__ __attribute__((aligned(16))) __bf16 hs0[16 * HSS];
    __shared__ __attribute__((aligned(16))) __bf16 hs1[16 * HSS];
    if (detect_isf(x))
        main_body<float>((const float*)x, (const float*)bn_g, (const float*)bn_b,
                         (const float*)w_in, ws, (float*)outv, hs0, hs1);
    else
        main_body<__bf16>((const __bf16*)x, (const __bf16*)bn_g, (const __bf16*)bn_b,
                          (const __bf16*)w_in, ws, (__bf16*)outv, hs0, hs1);
}

extern "C" void kernel_launch(void* const* d_in, const int* in_sizes, int n_in,
                              void* d_out, int out_size, void* d_ws, size_t ws_size,
                              hipStream_t stream) {
    float* ws = (float*)d_ws;
    hipMemsetAsync(d_ws, 0, 512, stream);   // zero the 128 stat accumulators
    stats_kernel<<<1024, 256, 0, stream>>>(d_in[0], d_in[1], d_in[5], d_in[6],
                                           d_in[7], d_in[8], d_in[9], d_in[10], ws);
    main_kernel<<<4096, 64, 0, stream>>>(d_in[0], d_in[3], d_in[4], d_in[1], ws, d_out);
}

// Round 5
// 176.655 us; speedup vs baseline: 1.3172x; 1.0235x over previous
//
#include <hip/hip_runtime.h>

typedef __attribute__((ext_vector_type(8))) __bf16 bf16x8;
typedef __attribute__((ext_vector_type(4))) float f32x4;
typedef unsigned short u16;
typedef unsigned int u32;

#define NB 524288
#define EPSI 1e-5f

__device__ __forceinline__ float bf2f(u16 h) {
    union { u32 u; float f; } cv; cv.u = ((u32)h) << 16; return cv.f;
}
__device__ __forceinline__ u16 f2bf(float f) {
    __bf16 b = (__bf16)f; return __builtin_bit_cast(u16, b);
}
__device__ __forceinline__ float ldany(const void* p, long i, int isf) {
    return isf ? ((const float*)p)[i] : bf2f(((const u16*)p)[i]);
}

// gelu_tanh = v * sigmoid(1.5957691*v*(1+0.044715 v^2)); |err| vs erf-gelu ~3e-4
__device__ __forceinline__ float fast_gelu(float v) {
    float t = 1.5957691216057308f * v * (1.0f + 0.044715f * v * v);
    float en = __expf(-t);
    return v * __builtin_amdgcn_rcpf(1.0f + en);
}

template<typename T>
__device__ __forceinline__ void load8f(const T* p, float* o);
template<>
__device__ __forceinline__ void load8f<__bf16>(const __bf16* p, float* o) {
    bf16x8 r = *reinterpret_cast<const bf16x8*>(p);
#pragma unroll
    for (int i = 0; i < 8; ++i) o[i] = (float)r[i];
}
template<>
__device__ __forceinline__ void load8f<float>(const float* p, float* o) {
    f32x4 a = *reinterpret_cast<const f32x4*>(p);
    f32x4 b = *reinterpret_cast<const f32x4*>(p + 4);
#pragma unroll
    for (int i = 0; i < 4; ++i) { o[i] = a[i]; o[4 + i] = b[i]; }
}

__device__ __forceinline__ bf16x8 loadfrag(const __bf16* p) {
    return *reinterpret_cast<const bf16x8*>(p);
}
__device__ __forceinline__ bf16x8 loadfrag(const float* p) {
    f32x4 a = *reinterpret_cast<const f32x4*>(p);
    f32x4 b = *reinterpret_cast<const f32x4*>(p + 4);
    bf16x8 r;
#pragma unroll
    for (int i = 0; i < 4; ++i) { r[i] = (__bf16)a[i]; r[4 + i] = (__bf16)b[i]; }
    return r;
}

// Per-wave dtype self-detect (f32-as-u16 low halves: ~25% have bf16-exp>=0xC0; true
// bf16 N(0,1): none). P(miss) < 1e-14 over 128 samples.
__device__ __forceinline__ int detect_isf(const void* x) {
    const int lane = threadIdx.x & 63;
    u32 w0 = ((const u32*)x)[lane];
    u32 w1 = ((const u32*)x)[64 + lane];
    int hit = ((((w0 >> 7) & 0xFFu) >= 0xC0u) || (((w1 >> 7) & 0xFFu) >= 0xC0u)) ? 1 : 0;
    return __ballot(hit) != 0ull;
}

// VALU-pipe rotation-add over each 16-lane row (DPP row_ror:N), replaces ds_swizzle
template<int CTRL>
__device__ __forceinline__ float dpp_rot_add(float v) {
    int s = __builtin_amdgcn_update_dpp(0, __builtin_bit_cast(int, v), CTRL, 0xF, 0xF, false);
    return v + __builtin_bit_cast(float, s);
}
__device__ __forceinline__ float row_reduce_add(float v) {
    v = dpp_rot_add<0x121>(v);   // row_ror:1
    v = dpp_rot_add<0x122>(v);   // row_ror:2
    v = dpp_rot_add<0x124>(v);   // row_ror:4
    v = dpp_rot_add<0x128>(v);   // row_ror:8
    return v;
}

// ---- stats (+pack): column sums/sumsq of h_pre = x @ w_in^T; blocks 0..24 also pack
template<typename T>
__device__ __forceinline__ void stats_body(const T* __restrict__ x,
                                           const T* __restrict__ w_in,
                                           float* __restrict__ ws,
                                           float* __restrict__ red) {
    const int lane = threadIdx.x & 63;
    const int wave = threadIdx.x >> 6;
    const int c = lane & 15;
    const int q = lane >> 4;

    bf16x8 b1[4];
#pragma unroll
    for (int nt = 0; nt < 4; ++nt)
        b1[nt] = loadfrag(w_in + (nt * 16 + c) * 32 + q * 8);

    float accs[4][4], accq[4][4];
#pragma unroll
    for (int nt = 0; nt < 4; ++nt)
#pragma unroll
        for (int r = 0; r < 4; ++r) { accs[nt][r] = 0.f; accq[nt][r] = 0.f; }

    const int wid = blockIdx.x * 4 + wave;  // 0..4095
    for (int t = 0; t < 8; ++t) {
        const long row0 = ((long)wid * 8 + t) * 16;
        bf16x8 a1 = loadfrag(x + (row0 + c) * 32 + q * 8);
#pragma unroll
        for (int nt = 0; nt < 4; ++nt) {
            f32x4 z = {0.f, 0.f, 0.f, 0.f};
            f32x4 acc = __builtin_amdgcn_mfma_f32_16x16x32_bf16(a1, b1[nt], z, 0, 0, 0);
#pragma unroll
            for (int r = 0; r < 4; ++r) {
                float v = acc[r];
                accs[nt][r] += v;
                accq[nt][r] += v * v;
            }
        }
    }
    for (int i = threadIdx.x; i < 128; i += 256) red[i] = 0.f;
    __syncthreads();
#pragma unroll
    for (int nt = 0; nt < 4; ++nt) {
        float s  = accs[nt][0] + accs[nt][1] + accs[nt][2] + accs[nt][3];
        float sq = accq[nt][0] + accq[nt][1] + accq[nt][2] + accq[nt][3];
        s  += __shfl_xor(s, 16);  s  += __shfl_xor(s, 32);
        sq += __shfl_xor(sq, 16); sq += __shfl_xor(sq, 32);
        if (q == 0) {
            atomicAdd(&red[nt * 16 + c], s);
            atomicAdd(&red[64 + nt * 16 + c], sq);
        }
    }
    __syncthreads();
    for (int i = threadIdx.x; i < 128; i += 256) atomicAdd(&ws[i], red[i]);
}

__global__ __launch_bounds__(256) void stats_kernel(
    const void* x, const void* w_in, const void* w_fi, const void* b_fi,
    const void* w_fs, const void* b_fs, const void* w_lc, const void* b_lc,
    float* __restrict__ ws)
{
    const int isf = detect_isf(x);

    // pack W2 (96x64 bf16, u/v leaf-pairs folded): blocks 0..23; biases: block 24
    if (blockIdx.x < 24) {
        u16* W2p = (u16*)(ws + 384);
        const int idx = blockIdx.x * 256 + threadIdx.x;   // 0..6143
        const int g = idx >> 6, f = idx & 63;
        float v = 0.f;
        if (g < 32)                 v = ldany(w_fi, (long)g * 64 + f, isf);
        else if (g < 64)            v = ldany(w_fs, (long)(g - 32) * 64 + f, isf);
        else if (g < 74)            v = ldany(w_lc, (long)(g - 64) * 64 + f, isf)
                                      + ldany(w_lc, (long)(g - 54) * 64 + f, isf);
        else if (g >= 80 && g < 90) v = ldany(w_lc, (long)(g - 60) * 64 + f, isf)
                                      + ldany(w_lc, (long)(g - 50) * 64 + f, isf);
        W2p[idx] = f2bf(v);
    } else if (blockIdx.x == 24 && threadIdx.x < 96) {
        float* biasP = ws + 288;
        const int g = threadIdx.x;
        float v = 0.f;
        if (g < 32)                 v = ldany(b_fi, g, isf);
        else if (g < 64)            v = ldany(b_fs, g - 32, isf);
        else if (g < 74)            v = ldany(b_lc, g - 64, isf) + ldany(b_lc, g - 54, isf);
        else if (g >= 80 && g < 90) v = ldany(b_lc, g - 60, isf) + ldany(b_lc, g - 50, isf);
        biasP[g] = v;
    }

    __shared__ float red[128];
    if (isf) stats_body<float>((const float*)x, (const float*)w_in, ws, red);
    else     stats_body<__bf16>((const __bf16*)x, (const __bf16*)w_in, ws, red);
}

// ---- main: LDS-free. GEMM1 transposed (A=W1-rows permuted by phi, B=x^T) so the
// C-layout output IS the A-fragment of GEMM2. phi(nt,m)=32(nt>>1)+8(m>>2)+4(nt&1)+(m&3).
template<typename T>
__device__ __forceinline__ void main_body(
    const T* __restrict__ x, const T* __restrict__ bn_g, const T* __restrict__ bn_b,
    const T* __restrict__ w_in, const float* __restrict__ ws, T* __restrict__ out)
{
    const int lane = threadIdx.x & 63;
    const int wave = threadIdx.x >> 6;
    const int c = lane & 15;
    const int q = lane >> 4;
    const float* biasP = ws + 288;
    const u16* W2p = (const u16*)(ws + 384);

    // A1-frags: row phi(nt,c), k=8q..8q+7, BN scale folded in (single bf16 rounding)
    bf16x8 b1[4];
#pragma unroll
    for (int nt = 0; nt < 4; ++nt) {
        const int row = 32 * (nt >> 1) + 8 * (c >> 2) + 4 * (nt & 1) + (c & 3);
        float mu  = ws[row] * (1.0f / NB);
        float var = fmaxf(ws[64 + row] * (1.0f / NB) - mu * mu, 0.0f);
        float s   = (float)bn_g[row] * rsqrtf(var + EPSI);
        float w8[8];
        load8f(w_in + row * 32 + q * 8, w8);
        bf16x8 f;
#pragma unroll
        for (int j = 0; j < 8; ++j) f[j] = (__bf16)(w8[j] * s);
        b1[nt] = f;
    }

    // per-element BN shift for feat phi(nt, 4q+r)
    float shift_t[4][4];
#pragma unroll
    for (int nt = 0; nt < 4; ++nt)
#pragma unroll
        for (int r = 0; r < 4; ++r) {
            const int ft = 32 * (nt >> 1) + 8 * q + 4 * (nt & 1) + r;
            float mu  = ws[ft] * (1.0f / NB);
            float var = fmaxf(ws[64 + ft] * (1.0f / NB) - mu * mu, 0.0f);
            float s   = (float)bn_g[ft] * rsqrtf(var + EPSI);
            shift_t[nt][r] = (float)bn_b[ft] - mu * s;
        }

    bf16x8 b2[6][2];
#pragma unroll
    for (int nt = 0; nt < 6; ++nt)
#pragma unroll
        for (int kt = 0; kt < 2; ++kt)
            b2[nt][kt] = *reinterpret_cast<const bf16x8*>(W2p + (nt * 16 + c) * 64 + kt * 32 + q * 8);

    const float bfi0 = biasP[c],      bfi1 = biasP[16 + c];
    const float bfs0 = biasP[32 + c], bfs1 = biasP[48 + c];
    const float bu   = biasP[64 + c], bv   = biasP[80 + c];

    const long gw = (long)blockIdx.x * 4 + wave;   // 0..4095, 128 rows each
#pragma unroll 2
    for (int t = 0; t < 8; ++t) {
        const long row0 = gw * 128 + (long)t * 16;
        // B-frag of GEMM1: B[k=8q+j][n=c] = x[row0+c][8q+j]
        bf16x8 a1 = loadfrag(x + (row0 + c) * 32 + q * 8);

        // epilogue x in C-layout (L1-hot, same lines as a1 across the wave)
        float xv0[4], xv1[4];
#pragma unroll
        for (int r = 0; r < 4; ++r) {
            xv0[r] = (float)x[(row0 + q * 4 + r) * 32 + c];
            xv1[r] = (float)x[(row0 + q * 4 + r) * 32 + 16 + c];
        }

        // GEMM1^T: lane(c,q) reg (nt,r) = s*h_pre[batch c][feat phi(nt,4q+r)]
        f32x4 h4[4];
#pragma unroll
        for (int nt = 0; nt < 4; ++nt) {
            f32x4 z = {0.f, 0.f, 0.f, 0.f};
            h4[nt] = __builtin_amdgcn_mfma_f32_16x16x32_bf16(b1[nt], a1, z, 0, 0, 0);
        }

        // shift + gelu; pack: a2_0[j=4nt+r]=g[nt][r] (nt 0..1), a2_1: nt 2..3
        bf16x8 a2_0, a2_1;
#pragma unroll
        for (int nt = 0; nt < 2; ++nt)
#pragma unroll
            for (int r = 0; r < 4; ++r) {
                a2_0[nt * 4 + r] = (__bf16)fast_gelu(h4[nt][r] + shift_t[nt][r]);
                a2_1[nt * 4 + r] = (__bf16)fast_gelu(h4[2 + nt][r] + shift_t[2 + nt][r]);
            }

        f32x4 acc[6];
#pragma unroll
        for (int nt = 0; nt < 6; ++nt) {
            f32x4 z = {0.f, 0.f, 0.f, 0.f};
            acc[nt] = __builtin_amdgcn_mfma_f32_16x16x32_bf16(a2_0, b2[nt][0], z, 0, 0, 0);
            acc[nt] = __builtin_amdgcn_mfma_f32_16x16x32_bf16(a2_1, b2[nt][1], acc[nt], 0, 0, 0);
        }

#pragma unroll
        for (int r = 0; r < 4; ++r) {
            // no max-subtraction: |fi| bounded << 87, f32 exp safe
            float e0  = __expf(acc[0][r] + bfi0);
            float e1  = __expf(acc[1][r] + bfi1);
            float fs0 = acc[2][r] + bfs0;
            float fs1 = acc[3][r] + bfs1;
            float es = row_reduce_add(e0 + e1);
            float dp = row_reduce_add(e0 * (xv0[r] - fs0) + e1 * (xv1[r] - fs1));
            float d  = dp * __builtin_amdgcn_rcpf(es);
            float sd = __builtin_amdgcn_rcpf(1.0f + __expf(-d));
            float uu = acc[4][r] + bu, vv = acc[5][r] + bv;
            float o = sd * (vv + sd * (uu - vv));  // sd^2*u + sd(1-sd)*v
            if (c < 10) out[(row0 + q * 4 + r) * 10 + c] = (T)o;
        }
    }
}

__global__ __launch_bounds__(256, 4) void main_kernel(
    const void* x, const void* bn_g, const void* bn_b, const void* w_in,
    float* ws, void* outv)
{
    if (detect_isf(x))
        main_body<float>((const float*)x, (const float*)bn_g, (const float*)bn_b,
                         (const float*)w_in, ws, (float*)outv);
    else
        main_body<__bf16>((const __bf16*)x, (const __bf16*)bn_g, (const __bf16*)bn_b,
                          (const __bf16*)w_in, ws, (__bf16*)outv);
}

extern "C" void kernel_launch(void* const* d_in, const int* in_sizes, int n_in,
                              void* d_out, int out_size, void* d_ws, size_t ws_size,
                              hipStream_t stream) {
    float* ws = (float*)d_ws;
    hipMemsetAsync(d_ws, 0, 512, stream);   // zero the 128 stat accumulators
    stats_kernel<<<1024, 256, 0, stream>>>(d_in[0], d_in[1], d_in[5], d_in[6],
                                           d_in[7], d_in[8], d_in[9], d_in[10], ws);
    main_kernel<<<1024, 256, 0, stream>>>(d_in[0], d_in[3], d_in[4], d_in[1], ws, d_out);
}